// Round 2
// baseline (1533.722 us; speedup 1.0000x reference)
//
#include <hip/hip_runtime.h>
#include <math.h>

// Problem constants
#define BATCH 2
#define SEQ 2048
#define DI 2048            // d_inner
#define DS 16              // d_state
#define DR 64              // dt_rank
#define P 96               // DR + 2*DS
#define BT_ROWS 4096       // BATCH*SEQ
#define NCH 64             // time chunks
#define CL 32              // chunk length (NCH*CL == SEQ)
#define KS 8               // split-K segments for proj1
#define KSEG 256           // 2048 / KS
#define LOG2E 1.4426950408889634f

#if __has_builtin(__builtin_amdgcn_exp2f)
__device__ __forceinline__ float fexp2(float x) { return __builtin_amdgcn_exp2f(x); }
#else
__device__ __forceinline__ float fexp2(float x) { return exp2f(x); }
#endif

// Workspace layout (floats).
//   xz:   [0,            393216)
//   hend: [393216,       4587520)   -- 2*64*16*2048; ALIASED: proj1 'parts'
//                                      (8*4096*96 = 3145728 floats) lives here;
//                                      dead before k_scan1 writes hend.
//   sd:   [4587520,      4849664)   -- 2*64*2048 per-chunk sum of delta
// total 4,849,664 floats = 18.5 MiB
#define WS_XZ   0
#define WS_HEND 393216
#define WS_SD   4587520

// ---------------- K1: xz partials, split-K GEMM ---------------------------
// C[bt][p] = sum_k x[bt][k] * w[p][k]; 32 rows x 96 cols per block.
__global__ __launch_bounds__(256) void k_proj1(const float* __restrict__ x,
                                               const float* __restrict__ w,
                                               float* __restrict__ parts) {
    __shared__ float Xt[32][36];    // [k][row], 144B pitch -> 16B-aligned float4 reads
    __shared__ float Wt[32][100];   // [k][p], stride-3 reads conflict-free
    const int tid = threadIdx.x;
    const int tx = tid & 31;        // p-group: p = tx*3 + {0,1,2}
    const int ty = tid >> 5;        // row-group: r = ty*4 + j
    const int row0 = blockIdx.x * 32;
    const int k0 = blockIdx.y * KSEG;
    const int kk = tid & 31;
    const int rr = tid >> 5;

    float acc[4][3];
#pragma unroll
    for (int j = 0; j < 4; ++j) { acc[j][0] = 0.f; acc[j][1] = 0.f; acc[j][2] = 0.f; }

    for (int kt = 0; kt < KSEG; kt += 32) {
#pragma unroll
        for (int j = 0; j < 4; ++j) {
            int r = rr + 8 * j;
            Xt[kk][r] = x[(size_t)(row0 + r) * DI + k0 + kt + kk];
        }
#pragma unroll
        for (int j = 0; j < 12; ++j) {
            int p = rr + 8 * j;
            Wt[kk][p] = w[(size_t)p * DI + k0 + kt + kk];
        }
        __syncthreads();
#pragma unroll
        for (int k = 0; k < 32; ++k) {
            float4 xa = *(const float4*)&Xt[k][ty * 4];
            float w0 = Wt[k][tx * 3 + 0];
            float w1 = Wt[k][tx * 3 + 1];
            float w2 = Wt[k][tx * 3 + 2];
            float xv[4] = {xa.x, xa.y, xa.z, xa.w};
#pragma unroll
            for (int j = 0; j < 4; ++j) {
                acc[j][0] = fmaf(xv[j], w0, acc[j][0]);
                acc[j][1] = fmaf(xv[j], w1, acc[j][1]);
                acc[j][2] = fmaf(xv[j], w2, acc[j][2]);
            }
        }
        __syncthreads();
    }
    float* out = parts + (size_t)blockIdx.y * BT_ROWS * P;
#pragma unroll
    for (int j = 0; j < 4; ++j) {
        int r = row0 + ty * 4 + j;
        out[(size_t)r * P + tx * 3 + 0] = acc[j][0];
        out[(size_t)r * P + tx * 3 + 1] = acc[j][1];
        out[(size_t)r * P + tx * 3 + 2] = acc[j][2];
    }
}

// ---------------- K1r: reduce split-K partials -> xz (float4) -------------
__global__ __launch_bounds__(256) void k_reduce(const float* __restrict__ parts,
                                                float* __restrict__ xz) {
    int i = (blockIdx.x * 256 + threadIdx.x) * 4;   // 98304 threads, grid 384
    float4 s = {0.f, 0.f, 0.f, 0.f};
#pragma unroll
    for (int k = 0; k < KS; ++k) {
        float4 v = *(const float4*)&parts[(size_t)k * BT_ROWS * P + i];
        s.x += v.x; s.y += v.y; s.z += v.z; s.w += v.w;
    }
    *(float4*)&xz[i] = s;
}

// ---------------- K2: delta = softplus(draw @ dtw^T + bias) ---------------
// Reads dt_proj_w rows directly (no transpose kernel): thread d preloads
// dtw[d][0..63] into 64 registers, fully unrolled inner product.
__global__ __launch_bounds__(256) void k_proj2(const float* __restrict__ xz,
                                               const float* __restrict__ dtw,
                                               const float* __restrict__ bias,
                                               float* __restrict__ delta) {
    __shared__ float draw_s[64][16];   // [r][row]
    const int tid = threadIdx.x;
    const int bt0 = blockIdx.x * 16;
    const int d = blockIdx.y * 256 + tid;

    for (int i = tid; i < 1024; i += 256) {
        int r = i & 63;
        int row = i >> 6;
        draw_s[r][row] = xz[(size_t)(bt0 + row) * P + r];
    }
    float wr[64];
    {
        const float4* wp = (const float4*)(dtw + (size_t)d * DR);
#pragma unroll
        for (int j = 0; j < 16; ++j) {
            float4 v = wp[j];
            wr[4 * j + 0] = v.x; wr[4 * j + 1] = v.y;
            wr[4 * j + 2] = v.z; wr[4 * j + 3] = v.w;
        }
    }
    __syncthreads();

    float acc[16];
#pragma unroll
    for (int j = 0; j < 16; ++j) acc[j] = 0.f;

#pragma unroll
    for (int r = 0; r < 64; ++r) {
        float w = wr[r];
        const float4* dr = (const float4*)&draw_s[r][0];
        float4 a0 = dr[0], a1 = dr[1], a2 = dr[2], a3 = dr[3];
        float vals[16] = {a0.x, a0.y, a0.z, a0.w, a1.x, a1.y, a1.z, a1.w,
                          a2.x, a2.y, a2.z, a2.w, a3.x, a3.y, a3.z, a3.w};
#pragma unroll
        for (int j = 0; j < 16; ++j) acc[j] = fmaf(vals[j], w, acc[j]);
    }
    float b = bias[d];
#pragma unroll
    for (int j = 0; j < 16; ++j) {
        float v = acc[j] + b;
        float sp = (v > 20.f) ? v : log1pf(__expf(v));
        delta[(size_t)(bt0 + j) * DI + d] = sp;
    }
}

// ---------------- K3: per-chunk local scan (h0=0) -> h_end, sum(delta) ----
__global__ __launch_bounds__(256) void k_scan1(const float* __restrict__ delta,
                                               const float* __restrict__ x,
                                               const float* __restrict__ xz,
                                               const float* __restrict__ A_log,
                                               float* __restrict__ hend,
                                               float* __restrict__ sdout) {
    __shared__ float Bs[CL][DS];
    const int tid = threadIdx.x;
    const int d = blockIdx.x * 256 + tid;
    const int c = blockIdx.y;
    const int b = blockIdx.z;
    const int btbase = b * SEQ + c * CL;

    for (int i = tid; i < CL * DS; i += 256) {
        int t = i >> 4;
        int n = i & 15;
        Bs[t][n] = xz[(size_t)(btbase + t) * P + DR + n];
    }
    float a2[16];
#pragma unroll
    for (int n = 0; n < 16; ++n)
        a2[n] = -__expf(A_log[(size_t)d * DS + n]) * LOG2E;   // negative; exp2 scale

    float h[16];
#pragma unroll
    for (int n = 0; n < 16; ++n) h[n] = 0.f;
    float sdsum = 0.f;
    __syncthreads();

    for (int t0 = 0; t0 < CL; t0 += 4) {
        float dv[4], xv[4];
#pragma unroll
        for (int j = 0; j < 4; ++j) {
            size_t gi = (size_t)(btbase + t0 + j) * DI + d;
            dv[j] = delta[gi];
            xv[j] = x[gi];
        }
#pragma unroll
        for (int j = 0; j < 4; ++j) {
            float dx = dv[j] * xv[j];
            sdsum += dv[j];
            const float4* bp = (const float4*)&Bs[t0 + j][0];
            float4 b0 = bp[0], b1 = bp[1], b2 = bp[2], b3 = bp[3];
            float bv[16] = {b0.x, b0.y, b0.z, b0.w, b1.x, b1.y, b1.z, b1.w,
                            b2.x, b2.y, b2.z, b2.w, b3.x, b3.y, b3.z, b3.w};
#pragma unroll
            for (int n = 0; n < 16; ++n) {
                h[n] = fmaf(fexp2(dv[j] * a2[n]), h[n], dx * bv[n]);
            }
        }
    }
    size_t base = ((size_t)((b * NCH + c) * DS)) * DI + d;
#pragma unroll
    for (int n = 0; n < 16; ++n) hend[base + (size_t)n * DI] = h[n];
    sdout[(size_t)(b * NCH + c) * DI + d] = sdsum;
}

// ---------------- K4: stitch chunk boundaries (hend -> h_start in place) --
__global__ __launch_bounds__(256) void k_stitch(float* __restrict__ hend,
                                                const float* __restrict__ sdin,
                                                const float* __restrict__ A_log) {
    int tid = blockIdx.x * 256 + threadIdx.x;   // 65536 threads
    int d = tid & (DI - 1);
    int n = (tid >> 11) & 15;
    int b = tid >> 15;
    float a2n = -__expf(A_log[(size_t)d * DS + n]) * LOG2E;
    float hs = 0.f;
    for (int c0 = 0; c0 < NCH; c0 += 4) {
        float he[4], sv[4];
#pragma unroll
        for (int j = 0; j < 4; ++j) {
            size_t idx = ((size_t)((b * NCH + c0 + j) * DS + n)) * DI + d;
            he[j] = hend[idx];
            sv[j] = sdin[(size_t)(b * NCH + c0 + j) * DI + d];
        }
#pragma unroll
        for (int j = 0; j < 4; ++j) {
            size_t idx = ((size_t)((b * NCH + c0 + j) * DS + n)) * DI + d;
            hend[idx] = hs;   // overwrite with h_start of this chunk
            hs = fmaf(fexp2(a2n * sv[j]), hs, he[j]);
        }
    }
}

// ---------------- K5: final scan with h_start, emit y (in-place over delta)
__global__ __launch_bounds__(256) void k_scan2(float* __restrict__ delta_y,
                                               const float* __restrict__ x,
                                               const float* __restrict__ xz,
                                               const float* __restrict__ A_log,
                                               const float* __restrict__ hstart,
                                               const float* __restrict__ Dw) {
    __shared__ float Bs[CL][DS];
    __shared__ float Cs[CL][DS];
    const int tid = threadIdx.x;
    const int d = blockIdx.x * 256 + tid;
    const int c = blockIdx.y;
    const int b = blockIdx.z;
    const int btbase = b * SEQ + c * CL;

    for (int i = tid; i < CL * DS; i += 256) {
        int t = i >> 4;
        int n = i & 15;
        Bs[t][n] = xz[(size_t)(btbase + t) * P + DR + n];
        Cs[t][n] = xz[(size_t)(btbase + t) * P + DR + DS + n];
    }
    float a2[16];
#pragma unroll
    for (int n = 0; n < 16; ++n)
        a2[n] = -__expf(A_log[(size_t)d * DS + n]) * LOG2E;

    size_t base = ((size_t)((b * NCH + c) * DS)) * DI + d;
    float h[16];
#pragma unroll
    for (int n = 0; n < 16; ++n) h[n] = hstart[base + (size_t)n * DI];
    float Dv = Dw[d];
    __syncthreads();

    for (int t0 = 0; t0 < CL; t0 += 4) {
        float dv[4], xv[4];
#pragma unroll
        for (int j = 0; j < 4; ++j) {
            size_t gi = (size_t)(btbase + t0 + j) * DI + d;
            dv[j] = delta_y[gi];
            xv[j] = x[gi];
        }
        float yv[4];
#pragma unroll
        for (int j = 0; j < 4; ++j) {
            float dx = dv[j] * xv[j];
            const float4* bp = (const float4*)&Bs[t0 + j][0];
            float4 b0 = bp[0], b1 = bp[1], b2 = bp[2], b3 = bp[3];
            const float4* cp = (const float4*)&Cs[t0 + j][0];
            float4 c0 = cp[0], c1 = cp[1], c2 = cp[2], c3 = cp[3];
            float bv[16] = {b0.x, b0.y, b0.z, b0.w, b1.x, b1.y, b1.z, b1.w,
                            b2.x, b2.y, b2.z, b2.w, b3.x, b3.y, b3.z, b3.w};
            float cv[16] = {c0.x, c0.y, c0.z, c0.w, c1.x, c1.y, c1.z, c1.w,
                            c2.x, c2.y, c2.z, c2.w, c3.x, c3.y, c3.z, c3.w};
            float y = Dv * xv[j];
#pragma unroll
            for (int n = 0; n < 16; ++n) {
                h[n] = fmaf(fexp2(dv[j] * a2[n]), h[n], dx * bv[n]);
                y = fmaf(h[n], cv[n], y);
            }
            yv[j] = y;
        }
#pragma unroll
        for (int j = 0; j < 4; ++j) {
            size_t gi = (size_t)(btbase + t0 + j) * DI + d;
            delta_y[gi] = yv[j];   // safe: this thread consumed delta[gi] above
        }
    }
}

extern "C" void kernel_launch(void* const* d_in, const int* in_sizes, int n_in,
                              void* d_out, int out_size, void* d_ws, size_t ws_size,
                              hipStream_t stream) {
    const float* x    = (const float*)d_in[0];   // (2,2048,2048)
    const float* xpw  = (const float*)d_in[1];   // (96,2048)
    const float* dtw  = (const float*)d_in[2];   // (2048,64)
    const float* dtb  = (const float*)d_in[3];   // (2048,)
    const float* Alog = (const float*)d_in[4];   // (2048,16)
    const float* Dw   = (const float*)d_in[5];   // (2048,)
    float* out = (float*)d_out;                  // holds delta, then y (in place)

    float* ws    = (float*)d_ws;
    float* xz    = ws + WS_XZ;
    float* hend  = ws + WS_HEND;
    float* parts = ws + WS_HEND;   // aliased: dead before hend is written
    float* sd    = ws + WS_SD;

    k_proj1<<<dim3(BT_ROWS / 32, KS), 256, 0, stream>>>(x, xpw, parts);
    k_reduce<<<dim3(BT_ROWS * P / 1024), 256, 0, stream>>>(parts, xz);
    k_proj2<<<dim3(BT_ROWS / 16, DI / 256), 256, 0, stream>>>(xz, dtw, dtb, out);
    k_scan1<<<dim3(DI / 256, NCH, BATCH), 256, 0, stream>>>(out, x, xz, Alog, hend, sd);
    k_stitch<<<dim3(BATCH * DS * DI / 256), 256, 0, stream>>>(hend, sd, Alog);
    k_scan2<<<dim3(DI / 256, NCH, BATCH), 256, 0, stream>>>(out, x, xz, Alog, hend, Dw);
}

// Round 3
// 226.955 us; speedup vs baseline: 6.7578x; 6.7578x over previous
//
#include <hip/hip_runtime.h>
#include <math.h>

// Problem constants
#define BATCH 2
#define SEQ 2048
#define DI 2048            // d_inner
#define DS 16              // d_state
#define DR 64              // dt_rank
#define P 96               // DR + 2*DS
#define BT_ROWS 4096       // BATCH*SEQ
#define NCH 64             // time chunks
#define CL 32              // chunk length (NCH*CL == SEQ)
#define KS 8               // split-K segments for proj1
#define KSEG 256           // 2048 / KS
#define LOG2E 1.4426950408889634f

#if __has_builtin(__builtin_amdgcn_exp2f)
__device__ __forceinline__ float fexp2(float x) { return __builtin_amdgcn_exp2f(x); }
#else
__device__ __forceinline__ float fexp2(float x) { return exp2f(x); }
#endif

// Workspace layout (floats).
//   xz:   [0,        393216)
//   hend: [393216,   4587520)  -- 2*64*16*2048; ALIASED with proj1 'parts'
//                                 (8*4096*96 = 3145728 floats), disjoint lifetime.
//   sd:   [4587520,  4849664)  -- 2*64*2048 per-chunk sum of delta
//   dtwT: [4849664,  4980736)  -- 64*2048 transposed dt_proj_w
// total 4,980,736 floats = 19.0 MiB
#define WS_XZ   0
#define WS_HEND 393216
#define WS_SD   4587520
#define WS_DTWT 4849664

// ---------------- K0: transpose dt_proj_w (2048x64) -> dtwT (64x2048) -----
__global__ __launch_bounds__(256) void k_transpose(const float* __restrict__ dtw,
                                                   float* __restrict__ dtwT) {
    int i = blockIdx.x * 256 + threadIdx.x;   // 131072 threads
    int d = i & (DI - 1);
    int r = i >> 11;
    dtwT[r * DI + d] = dtw[d * DR + r];       // coalesced write; tiny kernel
}

// ---------------- K1: xz partials, split-K GEMM ---------------------------
__global__ __launch_bounds__(256) void k_proj1(const float* __restrict__ x,
                                               const float* __restrict__ w,
                                               float* __restrict__ parts) {
    __shared__ float Xt[32][36];    // [k][row]
    __shared__ float Wt[32][100];   // [k][p]
    const int tid = threadIdx.x;
    const int tx = tid & 31;        // p-group: p = tx*3 + {0,1,2}
    const int ty = tid >> 5;        // row-group: r = ty*4 + j
    const int row0 = blockIdx.x * 32;
    const int k0 = blockIdx.y * KSEG;
    const int kk = tid & 31;
    const int rr = tid >> 5;

    float acc[4][3];
#pragma unroll
    for (int j = 0; j < 4; ++j) { acc[j][0] = 0.f; acc[j][1] = 0.f; acc[j][2] = 0.f; }

    for (int kt = 0; kt < KSEG; kt += 32) {
#pragma unroll
        for (int j = 0; j < 4; ++j) {
            int r = rr + 8 * j;
            Xt[kk][r] = x[(size_t)(row0 + r) * DI + k0 + kt + kk];
        }
#pragma unroll
        for (int j = 0; j < 12; ++j) {
            int p = rr + 8 * j;
            Wt[kk][p] = w[(size_t)p * DI + k0 + kt + kk];
        }
        __syncthreads();
#pragma unroll
        for (int k = 0; k < 32; ++k) {
            float4 xa = *(const float4*)&Xt[k][ty * 4];
            float w0 = Wt[k][tx * 3 + 0];
            float w1 = Wt[k][tx * 3 + 1];
            float w2 = Wt[k][tx * 3 + 2];
            float xv[4] = {xa.x, xa.y, xa.z, xa.w};
#pragma unroll
            for (int j = 0; j < 4; ++j) {
                acc[j][0] = fmaf(xv[j], w0, acc[j][0]);
                acc[j][1] = fmaf(xv[j], w1, acc[j][1]);
                acc[j][2] = fmaf(xv[j], w2, acc[j][2]);
            }
        }
        __syncthreads();
    }
    float* out = parts + (size_t)blockIdx.y * BT_ROWS * P;
#pragma unroll
    for (int j = 0; j < 4; ++j) {
        int r = row0 + ty * 4 + j;
        out[(size_t)r * P + tx * 3 + 0] = acc[j][0];
        out[(size_t)r * P + tx * 3 + 1] = acc[j][1];
        out[(size_t)r * P + tx * 3 + 2] = acc[j][2];
    }
}

// ---------------- K1r: reduce split-K partials -> xz (float4) -------------
__global__ __launch_bounds__(256) void k_reduce(const float* __restrict__ parts,
                                                float* __restrict__ xz) {
    int i = (blockIdx.x * 256 + threadIdx.x) * 4;
    float4 s = {0.f, 0.f, 0.f, 0.f};
#pragma unroll
    for (int k = 0; k < KS; ++k) {
        float4 v = *(const float4*)&parts[(size_t)k * BT_ROWS * P + i];
        s.x += v.x; s.y += v.y; s.z += v.z; s.w += v.w;
    }
    *(float4*)&xz[i] = s;
}

// ---------------- K2: delta = softplus(draw @ dtw^T + bias) ---------------
// Grid (BT_ROWS/16, DI/512), block 256. Thread owns 16 bt-rows x 2 d-cols.
// draw_s is [row][r]: staging writes are address-linear (no bank conflicts,
// coalesced global reads); compute reads are float4 broadcasts.
// Bounded unroll (4 r per iter) keeps VGPRs ~64 — NO spill (round-2 lesson).
__global__ __launch_bounds__(256) void k_proj2(const float* __restrict__ xz,
                                               const float* __restrict__ dtwT,
                                               const float* __restrict__ bias,
                                               float* __restrict__ delta) {
    __shared__ float draw_s[16][64];   // [row][r]
    const int tid = threadIdx.x;
    const int bt0 = blockIdx.x * 16;
    const int d0 = blockIdx.y * 512 + tid;   // this thread: d0 and d0+256

    for (int i = tid; i < 1024; i += 256) {
        int row = i >> 6;
        int r = i & 63;
        draw_s[row][r] = xz[(size_t)(bt0 + row) * P + r];   // linear LDS addr = i
    }
    __syncthreads();

    float acc0[16], acc1[16];
#pragma unroll
    for (int j = 0; j < 16; ++j) { acc0[j] = 0.f; acc1[j] = 0.f; }

    for (int r0 = 0; r0 < 64; r0 += 4) {
        float wa0 = dtwT[(size_t)(r0 + 0) * DI + d0];
        float wa1 = dtwT[(size_t)(r0 + 1) * DI + d0];
        float wa2 = dtwT[(size_t)(r0 + 2) * DI + d0];
        float wa3 = dtwT[(size_t)(r0 + 3) * DI + d0];
        float wb0 = dtwT[(size_t)(r0 + 0) * DI + d0 + 256];
        float wb1 = dtwT[(size_t)(r0 + 1) * DI + d0 + 256];
        float wb2 = dtwT[(size_t)(r0 + 2) * DI + d0 + 256];
        float wb3 = dtwT[(size_t)(r0 + 3) * DI + d0 + 256];
#pragma unroll
        for (int j = 0; j < 16; ++j) {
            float4 v = *(const float4*)&draw_s[j][r0];   // broadcast, 16B aligned
            acc0[j] = fmaf(v.x, wa0, acc0[j]);
            acc0[j] = fmaf(v.y, wa1, acc0[j]);
            acc0[j] = fmaf(v.z, wa2, acc0[j]);
            acc0[j] = fmaf(v.w, wa3, acc0[j]);
            acc1[j] = fmaf(v.x, wb0, acc1[j]);
            acc1[j] = fmaf(v.y, wb1, acc1[j]);
            acc1[j] = fmaf(v.z, wb2, acc1[j]);
            acc1[j] = fmaf(v.w, wb3, acc1[j]);
        }
    }
    float b0 = bias[d0];
    float b1 = bias[d0 + 256];
#pragma unroll
    for (int j = 0; j < 16; ++j) {
        float v0 = acc0[j] + b0;
        float v1 = acc1[j] + b1;
        float sp0 = (v0 > 20.f) ? v0 : log1pf(__expf(v0));
        float sp1 = (v1 > 20.f) ? v1 : log1pf(__expf(v1));
        delta[(size_t)(bt0 + j) * DI + d0] = sp0;
        delta[(size_t)(bt0 + j) * DI + d0 + 256] = sp1;
    }
}

// ---------------- K3: per-chunk local scan (h0=0) -> h_end, sum(delta) ----
__global__ __launch_bounds__(256) void k_scan1(const float* __restrict__ delta,
                                               const float* __restrict__ x,
                                               const float* __restrict__ xz,
                                               const float* __restrict__ A_log,
                                               float* __restrict__ hend,
                                               float* __restrict__ sdout) {
    __shared__ float Bs[CL][DS];
    const int tid = threadIdx.x;
    const int d = blockIdx.x * 256 + tid;
    const int c = blockIdx.y;
    const int b = blockIdx.z;
    const int btbase = b * SEQ + c * CL;

    for (int i = tid; i < CL * DS; i += 256) {
        int t = i >> 4;
        int n = i & 15;
        Bs[t][n] = xz[(size_t)(btbase + t) * P + DR + n];
    }
    float a2[16];
#pragma unroll
    for (int n = 0; n < 16; ++n)
        a2[n] = -__expf(A_log[(size_t)d * DS + n]) * LOG2E;

    float h[16];
#pragma unroll
    for (int n = 0; n < 16; ++n) h[n] = 0.f;
    float sdsum = 0.f;
    __syncthreads();

    for (int t0 = 0; t0 < CL; t0 += 4) {
        float dv[4], xv[4];
#pragma unroll
        for (int j = 0; j < 4; ++j) {
            size_t gi = (size_t)(btbase + t0 + j) * DI + d;
            dv[j] = delta[gi];
            xv[j] = x[gi];
        }
#pragma unroll
        for (int j = 0; j < 4; ++j) {
            float dx = dv[j] * xv[j];
            sdsum += dv[j];
            const float4* bp = (const float4*)&Bs[t0 + j][0];
            float4 b0 = bp[0], b1 = bp[1], b2 = bp[2], b3 = bp[3];
            float bv[16] = {b0.x, b0.y, b0.z, b0.w, b1.x, b1.y, b1.z, b1.w,
                            b2.x, b2.y, b2.z, b2.w, b3.x, b3.y, b3.z, b3.w};
#pragma unroll
            for (int n = 0; n < 16; ++n) {
                h[n] = fmaf(fexp2(dv[j] * a2[n]), h[n], dx * bv[n]);
            }
        }
    }
    size_t base = ((size_t)((b * NCH + c) * DS)) * DI + d;
#pragma unroll
    for (int n = 0; n < 16; ++n) hend[base + (size_t)n * DI] = h[n];
    sdout[(size_t)(b * NCH + c) * DI + d] = sdsum;
}

// ---------------- K4: stitch chunk boundaries (hend -> h_start in place) --
__global__ __launch_bounds__(256) void k_stitch(float* __restrict__ hend,
                                                const float* __restrict__ sdin,
                                                const float* __restrict__ A_log) {
    int tid = blockIdx.x * 256 + threadIdx.x;   // 65536 threads
    int d = tid & (DI - 1);
    int n = (tid >> 11) & 15;
    int b = tid >> 15;
    float a2n = -__expf(A_log[(size_t)d * DS + n]) * LOG2E;
    float hs = 0.f;
    for (int c0 = 0; c0 < NCH; c0 += 4) {
        float he[4], sv[4];
#pragma unroll
        for (int j = 0; j < 4; ++j) {
            size_t idx = ((size_t)((b * NCH + c0 + j) * DS + n)) * DI + d;
            he[j] = hend[idx];
            sv[j] = sdin[(size_t)(b * NCH + c0 + j) * DI + d];
        }
#pragma unroll
        for (int j = 0; j < 4; ++j) {
            size_t idx = ((size_t)((b * NCH + c0 + j) * DS + n)) * DI + d;
            hend[idx] = hs;   // overwrite with h_start of this chunk
            hs = fmaf(fexp2(a2n * sv[j]), hs, he[j]);
        }
    }
}

// ---------------- K5: final scan with h_start, emit y (in-place over delta)
__global__ __launch_bounds__(256) void k_scan2(float* __restrict__ delta_y,
                                               const float* __restrict__ x,
                                               const float* __restrict__ xz,
                                               const float* __restrict__ A_log,
                                               const float* __restrict__ hstart,
                                               const float* __restrict__ Dw) {
    __shared__ float Bs[CL][DS];
    __shared__ float Cs[CL][DS];
    const int tid = threadIdx.x;
    const int d = blockIdx.x * 256 + tid;
    const int c = blockIdx.y;
    const int b = blockIdx.z;
    const int btbase = b * SEQ + c * CL;

    for (int i = tid; i < CL * DS; i += 256) {
        int t = i >> 4;
        int n = i & 15;
        Bs[t][n] = xz[(size_t)(btbase + t) * P + DR + n];
        Cs[t][n] = xz[(size_t)(btbase + t) * P + DR + DS + n];
    }
    float a2[16];
#pragma unroll
    for (int n = 0; n < 16; ++n)
        a2[n] = -__expf(A_log[(size_t)d * DS + n]) * LOG2E;

    size_t base = ((size_t)((b * NCH + c) * DS)) * DI + d;
    float h[16];
#pragma unroll
    for (int n = 0; n < 16; ++n) h[n] = hstart[base + (size_t)n * DI];
    float Dv = Dw[d];
    __syncthreads();

    for (int t0 = 0; t0 < CL; t0 += 4) {
        float dv[4], xv[4];
#pragma unroll
        for (int j = 0; j < 4; ++j) {
            size_t gi = (size_t)(btbase + t0 + j) * DI + d;
            dv[j] = delta_y[gi];
            xv[j] = x[gi];
        }
        float yv[4];
#pragma unroll
        for (int j = 0; j < 4; ++j) {
            float dx = dv[j] * xv[j];
            const float4* bp = (const float4*)&Bs[t0 + j][0];
            float4 b0 = bp[0], b1 = bp[1], b2 = bp[2], b3 = bp[3];
            const float4* cp = (const float4*)&Cs[t0 + j][0];
            float4 c0 = cp[0], c1 = cp[1], c2 = cp[2], c3 = cp[3];
            float bv[16] = {b0.x, b0.y, b0.z, b0.w, b1.x, b1.y, b1.z, b1.w,
                            b2.x, b2.y, b2.z, b2.w, b3.x, b3.y, b3.z, b3.w};
            float cv[16] = {c0.x, c0.y, c0.z, c0.w, c1.x, c1.y, c1.z, c1.w,
                            c2.x, c2.y, c2.z, c2.w, c3.x, c3.y, c3.z, c3.w};
            float y = Dv * xv[j];
#pragma unroll
            for (int n = 0; n < 16; ++n) {
                h[n] = fmaf(fexp2(dv[j] * a2[n]), h[n], dx * bv[n]);
                y = fmaf(h[n], cv[n], y);
            }
            yv[j] = y;
        }
#pragma unroll
        for (int j = 0; j < 4; ++j) {
            size_t gi = (size_t)(btbase + t0 + j) * DI + d;
            delta_y[gi] = yv[j];   // safe: this thread consumed delta[gi] above
        }
    }
}

extern "C" void kernel_launch(void* const* d_in, const int* in_sizes, int n_in,
                              void* d_out, int out_size, void* d_ws, size_t ws_size,
                              hipStream_t stream) {
    const float* x    = (const float*)d_in[0];   // (2,2048,2048)
    const float* xpw  = (const float*)d_in[1];   // (96,2048)
    const float* dtw  = (const float*)d_in[2];   // (2048,64)
    const float* dtb  = (const float*)d_in[3];   // (2048,)
    const float* Alog = (const float*)d_in[4];   // (2048,16)
    const float* Dw   = (const float*)d_in[5];   // (2048,)
    float* out = (float*)d_out;                  // holds delta, then y (in place)

    float* ws    = (float*)d_ws;
    float* xz    = ws + WS_XZ;
    float* hend  = ws + WS_HEND;
    float* parts = ws + WS_HEND;   // aliased: dead before hend is written
    float* sd    = ws + WS_SD;
    float* dtwT  = ws + WS_DTWT;

    k_transpose<<<dim3(131072 / 256), 256, 0, stream>>>(dtw, dtwT);
    k_proj1<<<dim3(BT_ROWS / 32, KS), 256, 0, stream>>>(x, xpw, parts);
    k_reduce<<<dim3(BT_ROWS * P / 1024), 256, 0, stream>>>(parts, xz);
    k_proj2<<<dim3(BT_ROWS / 16, DI / 512), 256, 0, stream>>>(xz, dtwT, dtb, out);
    k_scan1<<<dim3(DI / 256, NCH, BATCH), 256, 0, stream>>>(out, x, xz, Alog, hend, sd);
    k_stitch<<<dim3(BATCH * DS * DI / 256), 256, 0, stream>>>(hend, sd, Alog);
    k_scan2<<<dim3(DI / 256, NCH, BATCH), 256, 0, stream>>>(out, x, xz, Alog, hend, Dw);
}